// Round 11
// baseline (351.975 us; speedup 1.0000x reference)
//
#include <hip/hip_runtime.h>
#include <math.h>

#define N_NODES 50000
#define N_EDGES 800000
#define NUM_GRAPHS_ 128
#define SCAN_NB 98   // ceil(50000/512)
#define NPASS 8
#define NODES_PER_PASS 6250   // 50000/8
#define HCHUNKS 64
#define EDGES_PER_CHUNK 12500 // 800000/64
#define HWORDS 12500          // 25000 nodes per half, 2 per word

typedef unsigned short u16;
typedef unsigned int u32;
typedef __attribute__((ext_vector_type(8))) short bf16x8;   // 8 bf16 (4 VGPRs)
typedef __attribute__((ext_vector_type(4))) float f32x4;    // 4 fp32

__device__ __forceinline__ float elu_f(float v) {
    return v > 0.f ? v : (__expf(v) - 1.f);
}
__device__ __forceinline__ u16 f2bf(float f) {  // RNE
    u32 u = __float_as_uint(f);
    u += 0x7FFFu + ((u >> 16) & 1u);
    return (u16)(u >> 16);
}
__device__ __forceinline__ float bf2f(u16 h) {
    return __uint_as_float(((u32)h) << 16);
}
__device__ __forceinline__ void bfpair(u32 v, float& lo, float& hi) {
    lo = __uint_as_float(v << 16);
    hi = __uint_as_float(v & 0xFFFF0000u);
}
__device__ __forceinline__ u32 packbf(float lo, float hi) {
    return (u32)f2bf(lo) | ((u32)f2bf(hi) << 16);
}
// unpack uint4 (8 bf16) -> 8 floats
__device__ __forceinline__ void unpack8(uint4 v, float* f) {
    bfpair(v.x, f[0], f[1]); bfpair(v.y, f[2], f[3]);
    bfpair(v.z, f[4], f[5]); bfpair(v.w, f[6], f[7]);
}

// ---------------------------------------------------------------------------
// Fused front-end: conv_x (3125 blocks) | ew+dst16 (3125) | pack_w (30)
// ---------------------------------------------------------------------------
__global__ __launch_bounds__(256) void prep_kernel(
    const float* __restrict__ x, u16* __restrict__ xb,
    const float* __restrict__ edge_attr, const float* __restrict__ w_fc1,
    const float* __restrict__ b_fc1, const int* __restrict__ edge_index,
    float* __restrict__ ew, u16* __restrict__ dst16,
    const float* __restrict__ w3_0, const float* __restrict__ w1_0, const float* __restrict__ w2_0,
    const float* __restrict__ w3_1, const float* __restrict__ w1_1, const float* __restrict__ w2_1,
    const float* __restrict__ w3_2, const float* __restrict__ w1_2, const float* __restrict__ w2_2,
    u16* __restrict__ bp0, u16* __restrict__ bp1, u16* __restrict__ bp2) {
    const int b = blockIdx.x;
    if (b < 3125) {
        // bf16 conversion of x
        int g = b * 256 + threadIdx.x;
        float4 v = ((const float4*)x)[g];
        uint2 o;
        o.x = packbf(v.x, v.y);
        o.y = packbf(v.z, v.w);
        ((uint2*)xb)[g] = o;
    } else if (b < 6250) {
        // edge weights + dst16
        int e = (b - 3125) * 256 + threadIdx.x;
        const float4* ea = (const float4*)(edge_attr + (size_t)e * 16);
        const float4* wf = (const float4*)w_fc1;
        float acc = b_fc1[0];
#pragma unroll
        for (int i = 0; i < 4; i++) {
            float4 a = ea[i], w = wf[i];
            acc += a.x * w.x + a.y * w.y + a.z * w.z + a.w * w.w;
        }
        ew[e] = acc;
        dst16[e] = (u16)edge_index[N_EDGES + e];
    } else {
        // pack weights into MFMA B-frag layout
        int t = (b - 6250) * 256 + threadIdx.x;
        if (t >= 7680) return;
        u16 buf[8];
        if (t < 4608) {
            int DIN, DOUT, lid;
            const float *w3, *w1, *w2;
            u16* bp;
            if (t < 1536) { DIN = 64; DOUT = 64;  lid = t;        w3 = w3_0; w1 = w1_0; w2 = w2_0; bp = bp0; }
            else          { DIN = 64; DOUT = 128; lid = t - 1536; w3 = w3_1; w1 = w1_1; w2 = w2_1; bp = bp1; }
            const int NT = DOUT / 16;
            const int lane = lid & 63;
            const int fragid = lid >> 6;
            const int chunk = fragid / NT;
            const int ntile = fragid % NT;
            const int n = ntile * 16 + (lane & 15);
            const int kbase = chunk * 32 + (lane >> 4) * 8;
#pragma unroll
            for (int j = 0; j < 8; j++) {
                int k = kbase + j;
                int region = k / DIN;
                int kk = k - region * DIN;
                float v = (region == 0) ? w3[kk * DOUT + n]
                        : (region == 1) ? w1[kk * DOUT + n]
                                        : -w2[kk * DOUT + n];
                buf[j] = f2bf(v);
            }
            *(bf16x8*)(bp + ((size_t)lid << 3)) = *(bf16x8*)buf;
        } else {
            // layer 2 wide: [w3 | -w2 | w1], K=128, DOUT=192
            const int lid = t - 4608;
            const int NT = 12;
            const int lane = lid & 63;
            const int fragid = lid >> 6;
            const int chunk = fragid / NT;
            const int ntile = fragid % NT;
            const int n = ntile * 16 + (lane & 15);
            const int kbase = chunk * 32 + (lane >> 4) * 8;
#pragma unroll
            for (int j = 0; j < 8; j++) {
                int k = kbase + j;
                float v = (n < 64)  ? w3_2[k * 64 + n]
                        : (n < 128) ? -w2_2[k * 64 + (n - 64)]
                                    : w1_2[k * 64 + (n - 128)];
                buf[j] = f2bf(v);
            }
            *(bf16x8*)(bp2 + ((size_t)lid << 3)) = *(bf16x8*)buf;
        }
    }
}

// ---------------------------------------------------------------------------
// Degree histogram per (chunk, half): LDS atomics only, dense write.
// ---------------------------------------------------------------------------
__global__ __launch_bounds__(256) void deg_hist_kernel(const u16* __restrict__ dst16,
                                                       u32* __restrict__ partial) {
    __shared__ u32 bins[HWORDS];
    const int c = blockIdx.x >> 1;
    const int p = blockIdx.x & 1;
    const int t = threadIdx.x;
    for (int i = t; i < HWORDS; i += 256) bins[i] = 0;
    __syncthreads();
    const int base = c * EDGES_PER_CHUNK;
    const int nlo = p * 25000;
    for (int i = t; i < EDGES_PER_CHUNK; i += 256) {
        const int b = (int)dst16[base + i] - nlo;
        if ((unsigned)b < 25000u)
            atomicAdd(&bins[b >> 1], 1u << ((b & 1) * 16));
    }
    __syncthreads();
    u32* outp = partial + (size_t)blockIdx.x * HWORDS;
    for (int i = t; i < HWORDS; i += 256) outp[i] = bins[i];
}

// ---------------------------------------------------------------------------
// Exclusive scan along chunk axis -> prefpack[c][pair], degpack (totals).
// ---------------------------------------------------------------------------
__global__ __launch_bounds__(256) void scan_chunks_kernel(const u32* __restrict__ partial,
                                                          u32* __restrict__ prefpack,
                                                          u32* __restrict__ degpack) {
    const int g = blockIdx.x * 256 + threadIdx.x;
    if (g >= 25000) return;
    const int p = (g >= HWORDS) ? 1 : 0;
    const int wh = g - p * HWORDS;
    u32 runlo = 0, runhi = 0;
    for (int c = 0; c < HCHUNKS; c++) {
        prefpack[(size_t)c * 25000 + g] = runlo | (runhi << 16);
        u32 v = partial[(size_t)((c << 1) + p) * HWORDS + wh];
        runlo += v & 0xFFFFu;
        runhi += v >> 16;
    }
    degpack[g] = runlo | (runhi << 16);
}

// ---------------------------------------------------------------------------
// Hierarchical exclusive scan of degpack -> rowptr[N+1]
// ---------------------------------------------------------------------------
__global__ __launch_bounds__(256) void scan1_kernel(const u32* __restrict__ degpack,
                                                    int* __restrict__ rowptr,
                                                    int* __restrict__ blk_sums) {
    __shared__ int sh[256];
    const int t = threadIdx.x;
    const int base = blockIdx.x * 512;
    const int i0 = base + 2 * t, i1 = i0 + 1;
    int d0 = 0, d1 = 0;
    if (i0 < N_NODES) {
        u32 v = degpack[i0 >> 1];
        d0 = (int)(v & 0xFFFFu);
        d1 = (int)(v >> 16);
    }
    const int pair = d0 + d1;
    int v = pair;
    sh[t] = v;
    __syncthreads();
#pragma unroll
    for (int off = 1; off < 256; off <<= 1) {
        int add = (t >= off) ? sh[t - off] : 0;
        __syncthreads();
        v += add;
        sh[t] = v;
        __syncthreads();
    }
    const int excl = v - pair;
    if (i0 < N_NODES) rowptr[i0] = excl;
    if (i1 < N_NODES) rowptr[i1] = excl + d0;
    if (t == 255) blk_sums[blockIdx.x] = v;
}

__global__ __launch_bounds__(128) void scan2_kernel(const int* __restrict__ blk_sums,
                                                    int* __restrict__ blk_offs,
                                                    int* __restrict__ rowptr) {
    __shared__ int sh[128];
    const int t = threadIdx.x;
    const int orig = (t < SCAN_NB) ? blk_sums[t] : 0;
    int v = orig;
    sh[t] = v;
    __syncthreads();
#pragma unroll
    for (int off = 1; off < 128; off <<= 1) {
        int add = (t >= off) ? sh[t - off] : 0;
        __syncthreads();
        v += add;
        sh[t] = v;
        __syncthreads();
    }
    if (t < SCAN_NB) blk_offs[t] = v - orig;
    if (t == 127) rowptr[N_NODES] = v;
}

__global__ void scan3_kernel(int* __restrict__ rowptr,
                             const int* __restrict__ blk_offs) {
    int i = blockIdx.x * blockDim.x + threadIdx.x;
    if (i >= N_NODES) return;
    rowptr[i] += blk_offs[i >> 9];
}

// ---------------------------------------------------------------------------
// CSR placement (counting sort, NO global atomics). Entry = {src:u16|w:bf16}.
// ---------------------------------------------------------------------------
__global__ __launch_bounds__(256) void place_kernel(const int* __restrict__ edge_index,
                                                    const float* __restrict__ ew,
                                                    const u16* __restrict__ dst16,
                                                    const int* __restrict__ rowptr,
                                                    const u32* __restrict__ prefpack,
                                                    u32* __restrict__ csr) {
    __shared__ int lcur[NODES_PER_PASS];
    const int pass = blockIdx.x & (NPASS - 1);
    const int c = blockIdx.x >> 3;
    const int lo = pass * NODES_PER_PASS;
    const int t = threadIdx.x;
    for (int i = t; i < NODES_PER_PASS; i += 256) lcur[i] = 0;
    __syncthreads();
    const int base = c * EDGES_PER_CHUNK;
    for (int i = t; i < EDGES_PER_CHUNK; i += 256) {
        const int e = base + i;
        const int d = (int)dst16[e];
        const int dl = d - lo;
        if ((unsigned)dl < (unsigned)NODES_PER_PASS) {
            u32 pw = prefpack[(size_t)c * 25000 + (d >> 1)];
            int pref = (int)((pw >> ((d & 1) * 16)) & 0xFFFFu);
            int lpos = atomicAdd(&lcur[dl], 1);
            u32 ent = (u32)(u16)edge_index[e] | ((u32)f2bf(ew[e]) << 16);
            csr[rowptr[d] + pref + lpos] = ent;
        }
    }
}

// ---------------------------------------------------------------------------
// Gather (64-dim, bf16, fp32 acc), one WAVE per node, CG=8 lanes/row (uint4),
// EG=8 edge-groups, 2x unroll => 16 load chains/wave.
// Writes s and ch = c*h; WRITE_C also emits c.
// ---------------------------------------------------------------------------
template <bool WRITE_C>
__global__ __launch_bounds__(256) void gather_kernel(
    const u16* __restrict__ xb, const int* __restrict__ rowptr,
    const u32* __restrict__ csr, u16* __restrict__ sb,
    u16* __restrict__ chb, float* __restrict__ c) {
    constexpr int CG = 8, EG = 8;
    const int gid = blockIdx.x * 256 + threadIdx.x;
    const int node = gid >> 6;
    if (node >= N_NODES) return;
    const int lane = threadIdx.x & 63;
    const int cg = lane & (CG - 1);
    const int eg = lane >> 3;
    const int beg = rowptr[node];
    const int end = rowptr[node + 1];
    const uint4* x4 = (const uint4*)xb;

    float a[8] = {}, b[8] = {};
    float wsum = 0.f;

    int p = beg + eg;
    for (; p + EG < end; p += 2 * EG) {
        u32 e0 = csr[p];
        u32 e1 = csr[p + EG];
        float w0 = bf2f((u16)(e0 >> 16));
        float w1 = bf2f((u16)(e1 >> 16));
        uint4 v0 = x4[(size_t)(e0 & 0xFFFFu) * CG + cg];
        uint4 v1 = x4[(size_t)(e1 & 0xFFFFu) * CG + cg];
        float f[8], g[8];
        unpack8(v0, f);
        unpack8(v1, g);
#pragma unroll
        for (int j = 0; j < 8; j++) { a[j] += w0 * f[j]; b[j] += w1 * g[j]; }
        wsum += w0 + w1;
    }
    if (p < end) {
        u32 e0 = csr[p];
        float w0 = bf2f((u16)(e0 >> 16));
        uint4 v0 = x4[(size_t)(e0 & 0xFFFFu) * CG + cg];
        float f[8];
        unpack8(v0, f);
#pragma unroll
        for (int j = 0; j < 8; j++) a[j] += w0 * f[j];
        wsum += w0;
    }
#pragma unroll
    for (int j = 0; j < 8; j++) a[j] += b[j];

    // reduce across edge-groups (offsets >= CG keep cg fixed)
#pragma unroll
    for (int off = 32; off >= CG; off >>= 1) {
#pragma unroll
        for (int j = 0; j < 8; j++) a[j] += __shfl_xor(a[j], off);
        wsum += __shfl_xor(wsum, off);
    }

    if (lane < CG) {
        uint4 so;
        so.x = packbf(a[0], a[1]);
        so.y = packbf(a[2], a[3]);
        so.z = packbf(a[4], a[5]);
        so.w = packbf(a[6], a[7]);
        ((uint4*)sb)[(size_t)node * CG + cg] = so;
        const float cn = WRITE_C ? wsum : c[node];
        uint4 hv = x4[(size_t)node * CG + cg];
        float h[8];
        unpack8(hv, h);
        uint4 co;
        co.x = packbf(cn * h[0], cn * h[1]);
        co.y = packbf(cn * h[2], cn * h[3]);
        co.z = packbf(cn * h[4], cn * h[5]);
        co.w = packbf(cn * h[6], cn * h[7]);
        ((uint4*)chb)[(size_t)node * CG + cg] = co;
    }
    if (WRITE_C && lane == 0) c[node] = wsum;
}

// ---------------------------------------------------------------------------
// MFMA GEMM (layers 0/1): out = elu( [h|s|ch] @ Bp + b3 + c*b1 )
// ---------------------------------------------------------------------------
template <int DIN, int DOUT>
__global__ __launch_bounds__(256) void gemm_mfma(
    const u16* __restrict__ hb, const u16* __restrict__ sb,
    const u16* __restrict__ chb, const u16* __restrict__ Bp,
    const float* __restrict__ cvec, const float* __restrict__ bias1,
    const float* __restrict__ bias3, u16* __restrict__ outp) {
    constexpr int CH = DIN / 32;
    constexpr int CHUNKS = 3 * CH;
    constexpr int NT = DOUT / 16;
    const int tid = threadIdx.x;
    const int wv = tid >> 6;
    const int lane = tid & 63;
    const int l15 = lane & 15;
    const int q = lane >> 4;
    const int row_base = blockIdx.x * 64 + (wv & 1) * 32;
    const int nt0 = blockIdx.y * 4 + (wv >> 1) * 2;

    const int r0 = min(row_base + l15, N_NODES - 1);
    const int r1 = min(row_base + 16 + l15, N_NODES - 1);
    const int qo = q * 8;

    f32x4 acc00 = {0.f, 0.f, 0.f, 0.f};
    f32x4 acc01 = {0.f, 0.f, 0.f, 0.f};
    f32x4 acc10 = {0.f, 0.f, 0.f, 0.f};
    f32x4 acc11 = {0.f, 0.f, 0.f, 0.f};

#pragma unroll
    for (int chunk = 0; chunk < CHUNKS; chunk++) {
        const int region = chunk / CH;
        const int koff = (chunk - region * CH) * 32 + qo;
        const u16* A = (region == 0) ? hb : (region == 1) ? sb : chb;
        bf16x8 a0 = *(const bf16x8*)(A + (size_t)r0 * DIN + koff);
        bf16x8 a1 = *(const bf16x8*)(A + (size_t)r1 * DIN + koff);
        const u16* bp = Bp + (((size_t)(chunk * NT + nt0) * 64 + lane) << 3);
        bf16x8 bf0 = *(const bf16x8*)bp;
        bf16x8 bf1 = *(const bf16x8*)(bp + 64 * 8);
        acc00 = __builtin_amdgcn_mfma_f32_16x16x32_bf16(a0, bf0, acc00, 0, 0, 0);
        acc01 = __builtin_amdgcn_mfma_f32_16x16x32_bf16(a0, bf1, acc01, 0, 0, 0);
        acc10 = __builtin_amdgcn_mfma_f32_16x16x32_bf16(a1, bf0, acc10, 0, 0, 0);
        acc11 = __builtin_amdgcn_mfma_f32_16x16x32_bf16(a1, bf1, acc11, 0, 0, 0);
    }

#pragma unroll
    for (int ni = 0; ni < 2; ni++) {
        const int col = (nt0 + ni) * 16 + l15;
        const float B3 = bias3[col];
        const float B1 = bias1[col];
        const f32x4 am0 = ni ? acc01 : acc00;
        const f32x4 am1 = ni ? acc11 : acc10;
#pragma unroll
        for (int mi = 0; mi < 2; mi++) {
            const f32x4 av = mi ? am1 : am0;
#pragma unroll
            for (int reg = 0; reg < 4; reg++) {
                const int row = row_base + mi * 16 + q * 4 + reg;
                if (row < N_NODES) {
                    const float cv = cvec[row];
                    const float val = av[reg] + B3 + cv * B1;
                    outp[(size_t)row * DOUT + col] = f2bf(elu_f(val));
                }
            }
        }
    }
}

// ---------------------------------------------------------------------------
// Layer-2 wide GEMM: zuy = h2 @ [w3 | -w2 | w1]  (K=128, DOUT=192)
// ---------------------------------------------------------------------------
__global__ __launch_bounds__(256) void gemm_wide_kernel(
    const u16* __restrict__ hb, const u16* __restrict__ Bp,
    u16* __restrict__ zuy) {
    constexpr int NT = 12;
    const int tid = threadIdx.x;
    const int wv = tid >> 6;
    const int lane = tid & 63;
    const int l15 = lane & 15;
    const int q = lane >> 4;
    const int row_base = blockIdx.x * 64 + (wv & 1) * 32;
    const int nt0 = blockIdx.y * 4 + (wv >> 1) * 2;

    const int r0 = min(row_base + l15, N_NODES - 1);
    const int r1 = min(row_base + 16 + l15, N_NODES - 1);
    const int qo = q * 8;

    f32x4 acc00 = {0.f, 0.f, 0.f, 0.f};
    f32x4 acc01 = {0.f, 0.f, 0.f, 0.f};
    f32x4 acc10 = {0.f, 0.f, 0.f, 0.f};
    f32x4 acc11 = {0.f, 0.f, 0.f, 0.f};

#pragma unroll
    for (int chunk = 0; chunk < 4; chunk++) {
        const int koff = chunk * 32 + qo;
        bf16x8 a0 = *(const bf16x8*)(hb + (size_t)r0 * 128 + koff);
        bf16x8 a1 = *(const bf16x8*)(hb + (size_t)r1 * 128 + koff);
        const u16* bp = Bp + (((size_t)(chunk * NT + nt0) * 64 + lane) << 3);
        bf16x8 bf0 = *(const bf16x8*)bp;
        bf16x8 bf1 = *(const bf16x8*)(bp + 64 * 8);
        acc00 = __builtin_amdgcn_mfma_f32_16x16x32_bf16(a0, bf0, acc00, 0, 0, 0);
        acc01 = __builtin_amdgcn_mfma_f32_16x16x32_bf16(a0, bf1, acc01, 0, 0, 0);
        acc10 = __builtin_amdgcn_mfma_f32_16x16x32_bf16(a1, bf0, acc10, 0, 0, 0);
        acc11 = __builtin_amdgcn_mfma_f32_16x16x32_bf16(a1, bf1, acc11, 0, 0, 0);
    }

#pragma unroll
    for (int ni = 0; ni < 2; ni++) {
        const int col = (nt0 + ni) * 16 + l15;
        const f32x4 am0 = ni ? acc01 : acc00;
        const f32x4 am1 = ni ? acc11 : acc10;
#pragma unroll
        for (int mi = 0; mi < 2; mi++) {
            const f32x4 av = mi ? am1 : am0;
#pragma unroll
            for (int reg = 0; reg < 4; reg++) {
                const int row = row_base + mi * 16 + q * 4 + reg;
                if (row < N_NODES)
                    zuy[(size_t)row * 192 + col] = f2bf(av[reg]);
            }
        }
    }
}

// ---------------------------------------------------------------------------
// Layer-2 gather + fused epilogue. zuy rows: [z(64) | u(64) | y(64)].
// h3 = elu( z + c*u + gather(y) + b3 + c*b1 ). CG=8 (uint4), EG=8.
// ---------------------------------------------------------------------------
__global__ __launch_bounds__(256) void gather2_kernel(
    const u16* __restrict__ zuy, const int* __restrict__ rowptr,
    const u32* __restrict__ csr, const float* __restrict__ c,
    const float* __restrict__ bias1, const float* __restrict__ bias3,
    u16* __restrict__ h3) {
    constexpr int CG = 8, EG = 8;
    const int gid = blockIdx.x * 256 + threadIdx.x;
    const int node = gid >> 6;
    if (node >= N_NODES) return;
    const int lane = threadIdx.x & 63;
    const int cg = lane & (CG - 1);
    const int eg = lane >> 3;
    const int beg = rowptr[node];
    const int end = rowptr[node + 1];

    float a[8] = {}, b[8] = {};

    int p = beg + eg;
    for (; p + EG < end; p += 2 * EG) {
        u32 e0 = csr[p];
        u32 e1 = csr[p + EG];
        float w0 = bf2f((u16)(e0 >> 16));
        float w1 = bf2f((u16)(e1 >> 16));
        uint4 v0 = ((const uint4*)(zuy + (size_t)(e0 & 0xFFFFu) * 192 + 128))[cg];
        uint4 v1 = ((const uint4*)(zuy + (size_t)(e1 & 0xFFFFu) * 192 + 128))[cg];
        float f[8], g[8];
        unpack8(v0, f);
        unpack8(v1, g);
#pragma unroll
        for (int j = 0; j < 8; j++) { a[j] += w0 * f[j]; b[j] += w1 * g[j]; }
    }
    if (p < end) {
        u32 e0 = csr[p];
        float w0 = bf2f((u16)(e0 >> 16));
        uint4 v0 = ((const uint4*)(zuy + (size_t)(e0 & 0xFFFFu) * 192 + 128))[cg];
        float f[8];
        unpack8(v0, f);
#pragma unroll
        for (int j = 0; j < 8; j++) a[j] += w0 * f[j];
    }
#pragma unroll
    for (int j = 0; j < 8; j++) a[j] += b[j];

#pragma unroll
    for (int off = 32; off >= CG; off >>= 1) {
#pragma unroll
        for (int j = 0; j < 8; j++) a[j] += __shfl_xor(a[j], off);
    }

    if (lane < CG) {
        const float cn = c[node];
        const u16* zr = zuy + (size_t)node * 192;
        uint4 zv = ((const uint4*)zr)[cg];
        uint4 uv = ((const uint4*)(zr + 64))[cg];
        float z[8], u[8];
        unpack8(zv, z);
        unpack8(uv, u);
        const float4 b3a = *(const float4*)(bias3 + cg * 8);
        const float4 b3b = *(const float4*)(bias3 + cg * 8 + 4);
        const float4 b1a = *(const float4*)(bias1 + cg * 8);
        const float4 b1b = *(const float4*)(bias1 + cg * 8 + 4);
        float b3v[8] = {b3a.x, b3a.y, b3a.z, b3a.w, b3b.x, b3b.y, b3b.z, b3b.w};
        float b1v[8] = {b1a.x, b1a.y, b1a.z, b1a.w, b1b.x, b1b.y, b1b.z, b1b.w};
        float o[8];
#pragma unroll
        for (int j = 0; j < 8; j++)
            o[j] = elu_f(z[j] + cn * u[j] + a[j] + b3v[j] + cn * b1v[j]);
        uint4 ov;
        ov.x = packbf(o[0], o[1]);
        ov.y = packbf(o[2], o[3]);
        ov.z = packbf(o[4], o[5]);
        ov.w = packbf(o[6], o[7]);
        ((uint4*)h3)[(size_t)node * CG + cg] = ov;
    }
}

// ---------------------------------------------------------------------------
// out[g, :] = max over nodes of graph g of h[:, :64] (bf16 in, fp32 out)
// ---------------------------------------------------------------------------
__global__ void pool_kernel(const u16* __restrict__ h,
                            const int* __restrict__ batch,
                            float* __restrict__ out) {
    const int g = blockIdx.x;
    const int tid = threadIdx.x;
    int lo = 0, hi = N_NODES;
    while (lo < hi) { int mid = (lo + hi) >> 1; if (batch[mid] < g) lo = mid + 1; else hi = mid; }
    const int beg = lo;
    lo = beg; hi = N_NODES;
    while (lo < hi) { int mid = (lo + hi) >> 1; if (batch[mid] < g + 1) lo = mid + 1; else hi = mid; }
    const int end = lo;

    __shared__ float red[256];
    const int col = tid & 63;
    const int rg = tid >> 6;
    float m = -3.0e38f;
    for (int r = beg + rg; r < end; r += 4) m = fmaxf(m, bf2f(h[(size_t)r * 64 + col]));
    red[tid] = m;
    __syncthreads();
    if (tid < 64) {
        m = fmaxf(fmaxf(red[tid], red[tid + 64]), fmaxf(red[tid + 128], red[tid + 192]));
        out[g * 64 + tid] = m;
    }
}

extern "C" void kernel_launch(void* const* d_in, const int* in_sizes, int n_in,
                              void* d_out, int out_size, void* d_ws, size_t ws_size,
                              hipStream_t stream) {
    const float* x = (const float*)d_in[0];
    const int* ei = (const int*)d_in[1];
    const float* ea = (const float*)d_in[2];
    const int* batch = (const int*)d_in[3];
    const float* wfc = (const float*)d_in[4];
    const float* bfc = (const float*)d_in[5];
    const float* w1_0 = (const float*)d_in[6];
    const float* b1_0 = (const float*)d_in[7];
    const float* w2_0 = (const float*)d_in[8];
    const float* w3_0 = (const float*)d_in[9];
    const float* b3_0 = (const float*)d_in[10];
    const float* w1_1 = (const float*)d_in[11];
    const float* b1_1 = (const float*)d_in[12];
    const float* w2_1 = (const float*)d_in[13];
    const float* w3_1 = (const float*)d_in[14];
    const float* b3_1 = (const float*)d_in[15];
    const float* w1_2 = (const float*)d_in[16];
    const float* b1_2 = (const float*)d_in[17];
    const float* w2_2 = (const float*)d_in[18];
    const float* w3_2 = (const float*)d_in[19];
    const float* b3_2 = (const float*)d_in[20];
    float* out = (float*)d_out;

    char* ws = (char*)d_ws;
    float* ew      = (float*)(ws);                 // E f32      3.2 MB
    float* c       = (float*)(ws + 3200000);       // N f32
    int*   rowptr  = (int*)  (ws + 3800000);       // N+1 int
    u32*   csr     = (u32*)  (ws + 4000128);       // E u32      3.2 MB
    u16*   xb      = (u16*)  (ws + 10400128);      // N*64 bf16  6.4 MB
    u16*   sb      = (u16*)  (ws + 16800128);      // N*128 bf16 12.8 MB
    u16*   chb     = (u16*)  (ws + 29600128);      // N*128 bf16 12.8 MB
    u16*   h1      = (u16*)  (ws + 42400128);      // N*64 bf16  6.4 MB
    u16*   h2      = (u16*)  (ws + 48800128);      // N*128 bf16 12.8 MB
    u16*   h3      = (u16*)  (ws + 61600128);      // N*64 bf16  6.4 MB
    u16*   bp0     = (u16*)  (ws + 68000128);      // 24 KB packed weights L0
    u16*   bp1     = (u16*)  (ws + 68024704);      // 48 KB L1
    u16*   bp2     = (u16*)  (ws + 68073856);      // 48 KB L2 wide
    int* blk_sums  = (int*)  (ws + 68123008);
    int* blk_offs  = (int*)  (ws + 68123520);
    // aliases into regions dead at time of use:
    u16* dst16   = chb;                        // 1.6 MB, dead before gather0
    u32* degpack = (u32*)(ws + 31600128);      // 100 KB (chb+2MB), dead before gather0
    u32* partial = (u32*)sb;                   // 6.4 MB, dead before gather0
    u32* prefpack = (u32*)h2;                  // 6.4 MB, dead before gemm L1 writes h2
    u16* zuy     = sb;                         // N*192 bf16 = 19.2 MB over sb+chb

    prep_kernel<<<6280, 256, 0, stream>>>(x, xb, ea, wfc, bfc, ei, ew, dst16,
                                          w3_0, w1_0, w2_0, w3_1, w1_1, w2_1,
                                          w3_2, w1_2, w2_2, bp0, bp1, bp2);
    deg_hist_kernel<<<HCHUNKS * 2, 256, 0, stream>>>(dst16, partial);
    scan_chunks_kernel<<<98, 256, 0, stream>>>(partial, prefpack, degpack);
    scan1_kernel<<<SCAN_NB, 256, 0, stream>>>(degpack, rowptr, blk_sums);
    scan2_kernel<<<1, 128, 0, stream>>>(blk_sums, blk_offs, rowptr);
    scan3_kernel<<<(N_NODES + 255) / 256, 256, 0, stream>>>(rowptr, blk_offs);
    place_kernel<<<HCHUNKS * NPASS, 256, 0, stream>>>(ei, ew, dst16, rowptr, prefpack, csr);

    const int RB = (N_NODES + 63) / 64;           // 782 row-blocks
    const int GBLK = (N_NODES * 64 + 255) / 256;  // one wave per node

    // layer 0: 64 -> 64
    gather_kernel<true><<<GBLK, 256, 0, stream>>>(xb, rowptr, csr, sb, chb, c);
    gemm_mfma<64, 64><<<dim3(RB, 1), 256, 0, stream>>>(xb, sb, chb, bp0, c, b1_0, b3_0, h1);

    // layer 1: 64 -> 128
    gather_kernel<false><<<GBLK, 256, 0, stream>>>(h1, rowptr, csr, sb, chb, c);
    gemm_mfma<64, 128><<<dim3(RB, 2), 256, 0, stream>>>(h1, sb, chb, bp1, c, b1_1, b3_1, h2);

    // layer 2: 128 -> 64, wide gemm then output-space gather w/ fused epilogue
    gemm_wide_kernel<<<dim3(RB, 3), 256, 0, stream>>>(h2, bp2, zuy);
    gather2_kernel<<<GBLK, 256, 0, stream>>>(zuy, rowptr, csr, c, b1_2, b3_2, h3);

    // global max pool
    pool_kernel<<<NUM_GRAPHS_, 256, 0, stream>>>(h3, batch, out);
}